// Round 1
// baseline (145.536 us; speedup 1.0000x reference)
//
#include <hip/hip_runtime.h>
#include <hip/hip_bf16.h>
#include <hip/hip_fp16.h>

// Sparse gather-FFN. Plateau analysis (R10-R12): main ~76.5us, DS pipe ~89%
// busy (8192 wave ds_read_b128/CU x ~12cyc + 27us conflicts), VALU 27us
// hidden, ~8-10us barrier/tail residual. Compiler already max-hoists gathers
// (R12: VGPR unchanged at 48).
// R13: two 8-row groups per block (RPB=16, valsA/valsB, 61.4KB LDS,
// 2 blocks/CU). One barrier serves 16 rows; idx/w fetched once per quartet.
// R14: bank-conflict-balancing prepass. The k-order within each unit is
// free (dot product commutes), and conflicts are per (slot, wave-of-64-
// units): bank group = idx & 7 (addr = idx*16). Counting-sort each unit's
// 16 (idx,w) pairs by bank group, then stratified per-lane rotation
// rot=(lane>>2) so each slot samples all 16 sorted positions evenly
// across the wave -> expected max group-load drops ~12 -> ~10.
// Predicted: SQ_LDS_BANK_CONFLICT -40..60%, main 76.5 -> ~65us.
// Main kernel UNCHANGED from R13 (clean A/B on the conflict theory).

#define NB   32768
#define NIN  128
#define NL   8
#define NW   256
#define NK   16
#define RPB  16                       // rows per block = 2 groups x 8
#define STORED (NIN + (NL - 1) * NW)  // 1920 features per group
#define NPARAM (NL * NW * NK)         // 32768 (l,u,k) entries

typedef __fp16 fp16v2 __attribute__((ext_vector_type(2)));

__device__ __forceinline__ unsigned pk16(float a, float b) {
    fp16v2 p = __builtin_amdgcn_cvt_pkrtz(a, b);   // v_cvt_pkrtz_f16_f32
    return __builtin_bit_cast(unsigned, p);
}

__device__ __forceinline__ __half2 as_h2(unsigned u) {
    return __builtin_bit_cast(__half2, u);
}

__device__ __forceinline__ float fast_sigmoid(float x) {
    return __builtin_amdgcn_rcpf(1.0f + __expf(-x));
}

// 8 row-MACs from one 16B packed-f16 word: 4x v_pk_fma_f16
__device__ __forceinline__ void fma_feat(__half2 acc[4], __half2 w2, uint4 p) {
    acc[0] = __hfma2(as_h2(p.x), w2, acc[0]);
    acc[1] = __hfma2(as_h2(p.y), w2, acc[1]);
    acc[2] = __hfma2(as_h2(p.z), w2, acc[2]);
    acc[3] = __hfma2(as_h2(p.w), w2, acc[3]);
}

template <bool PRE>
__global__ __launch_bounds__(256, 2)
void ffn_gather_kernel(const float* __restrict__ inputs,
                       const float* __restrict__ weights,
                       const float* __restrict__ biases,
                       const int*   __restrict__ edge_idx,
                       const int*   __restrict__ idxb,   // pre-scaled byte offs
                       const unsigned* __restrict__ wpk, // packed (w,w) f16
                       float* __restrict__ out)
{
    __shared__ uint4 valsA[STORED];   // group A: rows row0..row0+7
    __shared__ uint4 valsB[STORED];   // group B: rows row0+8..row0+15

    const int t = threadIdx.x;                       // 0..255, unit id
    const long long row0 = (long long)blockIdx.x * RPB;
    const char* vbaseA = (const char*)valsA;
    const char* vbaseB = (const char*)valsB;

    // ---- stage 128 input features x 16 rows: t<128 -> A, t>=128 -> B ----
    {
        const int f = t & 127;
        const long long r0 = row0 + ((t >> 7) << 3);   // +0 (A) or +8 (B)
        float v[8];
        #pragma unroll
        for (int r = 0; r < 8; ++r) v[r] = inputs[(r0 + r) * NIN + f];
        uint4 p;
        p.x = pk16(v[0], v[1]);
        p.y = pk16(v[2], v[3]);
        p.z = pk16(v[4], v[5]);
        p.w = pk16(v[6], v[7]);
        if (t < NIN) valsA[f] = p; else valsB[f] = p;
    }
    __syncthreads();

    // ---- layers ----
    #pragma unroll
    for (int l = 0; l < NL; ++l) {
        const int base = (l * NW + t) * NK;

        const float b = biases[l * NW + t];
        __half2 accA[4], accB[4];
        const __half2 bb = __float2half2_rn(b);
        #pragma unroll
        for (int j = 0; j < 4; ++j) { accA[j] = bb; accB[j] = bb; }

        #pragma unroll
        for (int kk = 0; kk < NK / 4; ++kk) {
            int4 o4;          // byte offsets into vals (shared by A and B!)
            __half2 w0, w1, w2, w3;
            if (PRE) {
                o4 = ((const int4*)(idxb + base))[kk];
                uint4 wp = ((const uint4*)(wpk + base))[kk];
                w0 = as_h2(wp.x); w1 = as_h2(wp.y);
                w2 = as_h2(wp.z); w3 = as_h2(wp.w);
            } else {
                int4 i4 = ((const int4*)(edge_idx + base))[kk];
                o4.x = i4.x << 4; o4.y = i4.y << 4;
                o4.z = i4.z << 4; o4.w = i4.w << 4;
                float4 w4 = ((const float4*)(weights + base))[kk];
                w0 = __float2half2_rn(w4.x);
                w1 = __float2half2_rn(w4.y);
                w2 = __float2half2_rn(w4.z);
                w3 = __float2half2_rn(w4.w);
            }
            // 8 independent gathers (two per feature, groups A+B)
            const uint4 a0 = *(const uint4*)(vbaseA + o4.x);
            const uint4 b0 = *(const uint4*)(vbaseB + o4.x);
            const uint4 a1 = *(const uint4*)(vbaseA + o4.y);
            const uint4 b1 = *(const uint4*)(vbaseB + o4.y);
            const uint4 a2 = *(const uint4*)(vbaseA + o4.z);
            const uint4 b2 = *(const uint4*)(vbaseB + o4.z);
            const uint4 a3 = *(const uint4*)(vbaseA + o4.w);
            const uint4 b3 = *(const uint4*)(vbaseB + o4.w);
            fma_feat(accA, w0, a0);
            fma_feat(accB, w0, b0);
            fma_feat(accA, w1, a1);
            fma_feat(accB, w1, b1);
            fma_feat(accA, w2, a2);
            fma_feat(accB, w2, b2);
            fma_feat(accA, w3, a3);
            fma_feat(accB, w3, b3);
        }

        float sA[8], sB[8];
        #pragma unroll
        for (int j = 0; j < 4; ++j) {
            sA[2 * j + 0] = fast_sigmoid(__low2float(accA[j]));
            sA[2 * j + 1] = fast_sigmoid(__high2float(accA[j]));
            sB[2 * j + 0] = fast_sigmoid(__low2float(accB[j]));
            sB[2 * j + 1] = fast_sigmoid(__high2float(accB[j]));
        }

        if (l < NL - 1) {
            uint4 pA, pB;
            pA.x = pk16(sA[0], sA[1]); pA.y = pk16(sA[2], sA[3]);
            pA.z = pk16(sA[4], sA[5]); pA.w = pk16(sA[6], sA[7]);
            pB.x = pk16(sB[0], sB[1]); pB.y = pk16(sB[2], sB[3]);
            pB.z = pk16(sB[4], sB[5]); pB.w = pk16(sB[6], sB[7]);
            valsA[NIN + l * NW + t] = pA;
            valsB[NIN + l * NW + t] = pB;
            __syncthreads();           // ONE barrier per 16 rows per layer
        } else {
            #pragma unroll
            for (int r = 0; r < 8; ++r) {
                out[(row0 + r) * NW + t]     = sA[r];
                out[(row0 + 8 + r) * NW + t] = sB[r];
            }
        }
    }
}

// R14 prepass: byte-offset indices + packed (w,w) f16 weights, with the
// k-slots of each unit PERMUTED to balance LDS bank groups across each
// wave of 64 units. Bank group of a gather = idx & 7 (16B entries on
// 32x4B banks). Counting-sort the 16 items by group, then rotate by
// rot=(lane>>2): slot s takes sorted position (s-rot)&15, so across the
// 16 rotation classes (4 lanes each) every slot samples all 16 sorted
// positions -> near-uniform group load (~8/group) per wave instruction.
// Any permutation is numerically a reordered f16 sum: same tolerance
// class as the existing kernel.
__global__ __launch_bounds__(256)
void balance_prepass_kernel(const float* __restrict__ weights,
                            const int* __restrict__ edge_idx,
                            int* __restrict__ idxb,
                            unsigned* __restrict__ wpk)
{
    const int t = blockIdx.x * 256 + threadIdx.x;   // 0..2047: unit (l*NW+u)
    const int lane = threadIdx.x & 63;              // u & 63 (main-kernel wave lane)
    const int base = t * NK;

    int   idxv[NK];
    float wv[NK];
    #pragma unroll
    for (int j = 0; j < NK; ++j) {
        idxv[j] = edge_idx[base + j];
        wv[j]   = weights[base + j];
    }

    // counting sort by bank group, 8x8-bit packed counters
    unsigned long long cntp = 0;
    #pragma unroll
    for (int j = 0; j < NK; ++j)
        cntp += 1ull << ((idxv[j] & 7) * 8);

    // per-byte inclusive prefix sum, then shift up one byte -> exclusive
    unsigned long long x = cntp;
    x += x << 8;
    x += x << 16;
    x += x << 32;
    unsigned long long cur = x << 8;     // cur byte g = #items with group < g

    const int rot = lane >> 2;           // 16 rotation classes, 4 lanes each
    #pragma unroll
    for (int j = 0; j < NK; ++j) {
        const int g   = idxv[j] & 7;
        const int pos = (int)((cur >> (g * 8)) & 0xFF);  // unique 0..15
        cur += 1ull << (g * 8);
        const int slot = (pos + rot) & 15;
        idxb[base + slot] = idxv[j] << 4;
        wpk [base + slot] = pk16(wv[j], wv[j]);
    }
}

extern "C" void kernel_launch(void* const* d_in, const int* in_sizes, int n_in,
                              void* d_out, int out_size, void* d_ws, size_t ws_size,
                              hipStream_t stream)
{
    const float* inputs   = (const float*)d_in[0];
    const float* weights  = (const float*)d_in[1];
    const float* biases   = (const float*)d_in[2];
    const int*   edge_idx = (const int*)d_in[3];
    float* out = (float*)d_out;

    dim3 grid(NB / RPB);   // 2048
    dim3 block(NW);        // 256

    const size_t need = (size_t)NPARAM * 4 * 2;     // 256 KB
    if (ws_size >= need) {
        int*      idxb = (int*)d_ws;
        unsigned* wpk  = (unsigned*)((char*)d_ws + (size_t)NPARAM * 4);
        balance_prepass_kernel<<<NL * NW / 256, 256, 0, stream>>>(
            weights, edge_idx, idxb, wpk);
        ffn_gather_kernel<true><<<grid, block, 0, stream>>>(
            inputs, weights, biases, edge_idx, idxb, wpk, out);
    } else {
        ffn_gather_kernel<false><<<grid, block, 0, stream>>>(
            inputs, weights, biases, edge_idx, nullptr, nullptr, out);
    }
}

// Round 2
// 134.075 us; speedup vs baseline: 1.0855x; 1.0855x over previous
//
#include <hip/hip_runtime.h>
#include <hip/hip_bf16.h>
#include <hip/hip_fp16.h>

// Sparse gather-FFN. Plateau analysis (R10-R12): main kernel DS-pipe bound:
// 8192 wave ds_read_b128/CU (~12cyc each, ~41us) + bank conflicts, VALU
// ~26us hidden underneath, ~8-10us barrier/tail.
// R13: two 8-row groups per block (RPB=16, valsA/valsB, 60KB LDS,
// 2 blocks/CU). One barrier serves 16 rows; idx/w fetched once per quartet.
// R14 (FAILED, kept as evidence): bank-balancing prepass with rot=lane>>2
// RAISED SQ_LDS_BANK_CONFLICT 1.66e7 -> 2.20e7 and main 76.5 -> 99us.
// Post-mortem: conflicts are judged within phase groups of ~8 CONSECUTIVE
// lanes (8 lanes x 16B = 128B = all 32 banks per cycle), not across the
// wave. rot=lane>>2 made all 8 lanes of a phase read the same sorted
// position -> same 1-2 bank groups -> pile-up.
// R15: rot = (2*(lane&7) + (lane>>3)) & 15. Within 8 consecutive lanes:
// 8 distinct sorted positions spaced 2 apart -> ~8 distinct bank groups
// (position p maps to group ~p/2 after the counting sort). The +(lane>>3)
// term makes 16-consecutive-lane phases cover all 16 positions (<=2-way,
// near-free) and keeps interleaved phase hypotheses <=2-way. Predicted:
// SQ_LDS_BANK_CONFLICT <=1.1e7, main ~75-82us.
// Main kernel UNCHANGED (clean A/B on the rotation alone).

#define NB   32768
#define NIN  128
#define NL   8
#define NW   256
#define NK   16
#define RPB  16                       // rows per block = 2 groups x 8
#define STORED (NIN + (NL - 1) * NW)  // 1920 features per group
#define NPARAM (NL * NW * NK)         // 32768 (l,u,k) entries

typedef __fp16 fp16v2 __attribute__((ext_vector_type(2)));

__device__ __forceinline__ unsigned pk16(float a, float b) {
    fp16v2 p = __builtin_amdgcn_cvt_pkrtz(a, b);   // v_cvt_pkrtz_f16_f32
    return __builtin_bit_cast(unsigned, p);
}

__device__ __forceinline__ __half2 as_h2(unsigned u) {
    return __builtin_bit_cast(__half2, u);
}

__device__ __forceinline__ float fast_sigmoid(float x) {
    return __builtin_amdgcn_rcpf(1.0f + __expf(-x));
}

// 8 row-MACs from one 16B packed-f16 word: 4x v_pk_fma_f16
__device__ __forceinline__ void fma_feat(__half2 acc[4], __half2 w2, uint4 p) {
    acc[0] = __hfma2(as_h2(p.x), w2, acc[0]);
    acc[1] = __hfma2(as_h2(p.y), w2, acc[1]);
    acc[2] = __hfma2(as_h2(p.z), w2, acc[2]);
    acc[3] = __hfma2(as_h2(p.w), w2, acc[3]);
}

template <bool PRE>
__global__ __launch_bounds__(256, 2)
void ffn_gather_kernel(const float* __restrict__ inputs,
                       const float* __restrict__ weights,
                       const float* __restrict__ biases,
                       const int*   __restrict__ edge_idx,
                       const int*   __restrict__ idxb,   // pre-scaled byte offs
                       const unsigned* __restrict__ wpk, // packed (w,w) f16
                       float* __restrict__ out)
{
    __shared__ uint4 valsA[STORED];   // group A: rows row0..row0+7
    __shared__ uint4 valsB[STORED];   // group B: rows row0+8..row0+15

    const int t = threadIdx.x;                       // 0..255, unit id
    const long long row0 = (long long)blockIdx.x * RPB;
    const char* vbaseA = (const char*)valsA;
    const char* vbaseB = (const char*)valsB;

    // ---- stage 128 input features x 16 rows: t<128 -> A, t>=128 -> B ----
    {
        const int f = t & 127;
        const long long r0 = row0 + ((t >> 7) << 3);   // +0 (A) or +8 (B)
        float v[8];
        #pragma unroll
        for (int r = 0; r < 8; ++r) v[r] = inputs[(r0 + r) * NIN + f];
        uint4 p;
        p.x = pk16(v[0], v[1]);
        p.y = pk16(v[2], v[3]);
        p.z = pk16(v[4], v[5]);
        p.w = pk16(v[6], v[7]);
        if (t < NIN) valsA[f] = p; else valsB[f] = p;
    }
    __syncthreads();

    // ---- layers ----
    #pragma unroll
    for (int l = 0; l < NL; ++l) {
        const int base = (l * NW + t) * NK;

        const float b = biases[l * NW + t];
        __half2 accA[4], accB[4];
        const __half2 bb = __float2half2_rn(b);
        #pragma unroll
        for (int j = 0; j < 4; ++j) { accA[j] = bb; accB[j] = bb; }

        #pragma unroll
        for (int kk = 0; kk < NK / 4; ++kk) {
            int4 o4;          // byte offsets into vals (shared by A and B!)
            __half2 w0, w1, w2, w3;
            if (PRE) {
                o4 = ((const int4*)(idxb + base))[kk];
                uint4 wp = ((const uint4*)(wpk + base))[kk];
                w0 = as_h2(wp.x); w1 = as_h2(wp.y);
                w2 = as_h2(wp.z); w3 = as_h2(wp.w);
            } else {
                int4 i4 = ((const int4*)(edge_idx + base))[kk];
                o4.x = i4.x << 4; o4.y = i4.y << 4;
                o4.z = i4.z << 4; o4.w = i4.w << 4;
                float4 w4 = ((const float4*)(weights + base))[kk];
                w0 = __float2half2_rn(w4.x);
                w1 = __float2half2_rn(w4.y);
                w2 = __float2half2_rn(w4.z);
                w3 = __float2half2_rn(w4.w);
            }
            // 8 independent gathers (two per feature, groups A+B)
            const uint4 a0 = *(const uint4*)(vbaseA + o4.x);
            const uint4 b0 = *(const uint4*)(vbaseB + o4.x);
            const uint4 a1 = *(const uint4*)(vbaseA + o4.y);
            const uint4 b1 = *(const uint4*)(vbaseB + o4.y);
            const uint4 a2 = *(const uint4*)(vbaseA + o4.z);
            const uint4 b2 = *(const uint4*)(vbaseB + o4.z);
            const uint4 a3 = *(const uint4*)(vbaseA + o4.w);
            const uint4 b3 = *(const uint4*)(vbaseB + o4.w);
            fma_feat(accA, w0, a0);
            fma_feat(accB, w0, b0);
            fma_feat(accA, w1, a1);
            fma_feat(accB, w1, b1);
            fma_feat(accA, w2, a2);
            fma_feat(accB, w2, b2);
            fma_feat(accA, w3, a3);
            fma_feat(accB, w3, b3);
        }

        float sA[8], sB[8];
        #pragma unroll
        for (int j = 0; j < 4; ++j) {
            sA[2 * j + 0] = fast_sigmoid(__low2float(accA[j]));
            sA[2 * j + 1] = fast_sigmoid(__high2float(accA[j]));
            sB[2 * j + 0] = fast_sigmoid(__low2float(accB[j]));
            sB[2 * j + 1] = fast_sigmoid(__high2float(accB[j]));
        }

        if (l < NL - 1) {
            uint4 pA, pB;
            pA.x = pk16(sA[0], sA[1]); pA.y = pk16(sA[2], sA[3]);
            pA.z = pk16(sA[4], sA[5]); pA.w = pk16(sA[6], sA[7]);
            pB.x = pk16(sB[0], sB[1]); pB.y = pk16(sB[2], sB[3]);
            pB.z = pk16(sB[4], sB[5]); pB.w = pk16(sB[6], sB[7]);
            valsA[NIN + l * NW + t] = pA;
            valsB[NIN + l * NW + t] = pB;
            __syncthreads();           // ONE barrier per 16 rows per layer
        } else {
            #pragma unroll
            for (int r = 0; r < 8; ++r) {
                out[(row0 + r) * NW + t]     = sA[r];
                out[(row0 + 8 + r) * NW + t] = sB[r];
            }
        }
    }
}

// R15 prepass: byte-offset indices + packed (w,w) f16 weights, with the
// k-slots of each unit PERMUTED to balance LDS bank groups within each
// ~8-consecutive-lane phase group of a ds_read_b128 (R14 post-mortem:
// conflicts are per phase group, not per wave). Counting-sort the 16
// (idx,w) pairs by bank group (idx & 7), then rotate by
// rot = (2*(lane&7) + (lane>>3)) & 15: any 8 consecutive lanes read 8
// sorted positions spaced 2 apart -> ~8 distinct bank groups; any 16
// consecutive lanes cover all 16 positions (<=2-way, near-free).
// Numerically just a reordered f16 sum - same tolerance class.
__global__ __launch_bounds__(256)
void balance_prepass_kernel(const float* __restrict__ weights,
                            const int* __restrict__ edge_idx,
                            int* __restrict__ idxb,
                            unsigned* __restrict__ wpk)
{
    const int t = blockIdx.x * 256 + threadIdx.x;   // 0..2047: unit (l*NW+u)
    const int lane = threadIdx.x & 63;              // u & 63 (main-kernel wave lane)
    const int base = t * NK;

    int   idxv[NK];
    float wv[NK];
    #pragma unroll
    for (int j = 0; j < NK; ++j) {
        idxv[j] = edge_idx[base + j];
        wv[j]   = weights[base + j];
    }

    // counting sort by bank group, 8x8-bit packed counters
    unsigned long long cntp = 0;
    #pragma unroll
    for (int j = 0; j < NK; ++j)
        cntp += 1ull << ((idxv[j] & 7) * 8);

    // per-byte inclusive prefix sum, then shift up one byte -> exclusive
    unsigned long long x = cntp;
    x += x << 8;
    x += x << 16;
    x += x << 32;
    unsigned long long cur = x << 8;     // cur byte g = #items with group < g

    // R15 rotation: distinct spaced-2 positions within any 8 consecutive
    // lanes; full 16-position coverage within any 16 consecutive lanes.
    const int rot = (2 * (lane & 7) + ((lane >> 3) & 7)) & 15;
    #pragma unroll
    for (int j = 0; j < NK; ++j) {
        const int g   = idxv[j] & 7;
        const int pos = (int)((cur >> (g * 8)) & 0xFF);  // unique 0..15
        cur += 1ull << (g * 8);
        const int slot = (pos + rot) & 15;
        idxb[base + slot] = idxv[j] << 4;
        wpk [base + slot] = pk16(wv[j], wv[j]);
    }
}

extern "C" void kernel_launch(void* const* d_in, const int* in_sizes, int n_in,
                              void* d_out, int out_size, void* d_ws, size_t ws_size,
                              hipStream_t stream)
{
    const float* inputs   = (const float*)d_in[0];
    const float* weights  = (const float*)d_in[1];
    const float* biases   = (const float*)d_in[2];
    const int*   edge_idx = (const int*)d_in[3];
    float* out = (float*)d_out;

    dim3 grid(NB / RPB);   // 2048
    dim3 block(NW);        // 256

    const size_t need = (size_t)NPARAM * 4 * 2;     // 256 KB
    if (ws_size >= need) {
        int*      idxb = (int*)d_ws;
        unsigned* wpk  = (unsigned*)((char*)d_ws + (size_t)NPARAM * 4);
        balance_prepass_kernel<<<NL * NW / 256, 256, 0, stream>>>(
            weights, edge_idx, idxb, wpk);
        ffn_gather_kernel<true><<<grid, block, 0, stream>>>(
            inputs, weights, biases, edge_idx, idxb, wpk, out);
    } else {
        ffn_gather_kernel<false><<<grid, block, 0, stream>>>(
            inputs, weights, biases, edge_idx, nullptr, nullptr, out);
    }
}